// Round 7
// baseline (1388.585 us; speedup 1.0000x reference)
//
#include <hip/hip_runtime.h>
#include <hip/hip_bf16.h>

// Problem constants
#define BB 8
#define CC 256
#define ICC 128
#define HH 64
#define WW 64
#define NN 4096   // HH*WW
#define MM 1024   // pooled
#define BN_EPS 1e-5

// ---------------- workspace layout (float offsets) --------------------------
// TOTAL ws use: 1,114,112 floats = 4.25 MB (R4/R5 used 17.04 MB — suspected
// overflow of ws_size; phi_pooled now staged in d_out, gq fused on the fly).
#define WS_WT    0L         // weff[256], bias at [256]
#define WS_SPS   1024L      // 8*1024 s_p
#define WS_ST    16384L     // 8*4096 s_t
#define WS_SACC  49152L     // double[256] sum(P)   (512 floats)
#define WS_SACC2 49664L     // double[256] sum(P^2) (512 floats)
#define WS_AB    50176L     // am[256], sh[256]
#define WS_GP    65536L     // 8*128*1024 pooled g  -> ends 1114112

// ---------------- collapsed theta weights -----------------------------------
__global__ void k_weff(const float* __restrict__ cp_w,
                       const float* __restrict__ theta_w,
                       const float* __restrict__ theta_b,
                       float* __restrict__ weff) {
    int ch = threadIdx.x;  // 0..255
    float acc = 0.f;
    for (int c = 0; c < ICC; ++c) acc += cp_w[c] * theta_w[c * CC + ch];
    weff[ch] = acc;
    if (ch == 0) {
        float bt = 0.f;
        for (int c = 0; c < ICC; ++c) bt += cp_w[c] * theta_b[c];
        weff[256] = bt;
    }
}

// ---------------- conv1x1 (128 out ch) + 2x2 maxpool, fp32 tiled ------------
// grid (32 row-pairs, 2 oc-tiles, 8 b), block (32,8)
__global__ __launch_bounds__(256) void k_convpool(
    const float* __restrict__ x, const float* __restrict__ w,
    const float* __restrict__ bias, float* __restrict__ outp) {
    __shared__ float Xs[16][128];
    __shared__ float WsT[16][64];
    const int tx = threadIdx.x, ty = threadIdx.y;
    const int tid = ty * 32 + tx;
    const int rp = blockIdx.x;
    const int oc0 = blockIdx.y * 64;
    const int b = blockIdx.z;
    const long xbase = (long)b * CC * NN + rp * 128;

    float acc[8][4];
#pragma unroll
    for (int i = 0; i < 8; ++i)
#pragma unroll
        for (int j = 0; j < 4; ++j) acc[i][j] = 0.f;

    for (int k0 = 0; k0 < CC; k0 += 16) {
#pragma unroll
        for (int r = 0; r < 8; ++r) {
            int idx = r * 256 + tid;
            int kk = idx >> 7, px = idx & 127;
            Xs[kk][px] = x[xbase + (long)(k0 + kk) * NN + px];
        }
#pragma unroll
        for (int r = 0; r < 4; ++r) {
            int idx = r * 256 + tid;
            int kk = idx >> 6, oc = idx & 63;
            WsT[kk][oc] = w[(oc0 + oc) * CC + k0 + kk];
        }
        __syncthreads();
#pragma unroll
        for (int kk = 0; kk < 16; ++kk) {
            float4 xv = *reinterpret_cast<const float4*>(&Xs[kk][tx * 4]);
            float4 w0 = *reinterpret_cast<const float4*>(&WsT[kk][ty * 8]);
            float4 w1 = *reinterpret_cast<const float4*>(&WsT[kk][ty * 8 + 4]);
            const float wv[8] = {w0.x, w0.y, w0.z, w0.w, w1.x, w1.y, w1.z, w1.w};
#pragma unroll
            for (int i = 0; i < 8; ++i) {
                acc[i][0] += wv[i] * xv.x;
                acc[i][1] += wv[i] * xv.y;
                acc[i][2] += wv[i] * xv.z;
                acc[i][3] += wv[i] * xv.w;
            }
        }
        __syncthreads();
    }
#pragma unroll
    for (int i = 0; i < 8; ++i) {
        float bv = bias[oc0 + ty * 8 + i];
        float m0 = fmaxf(acc[i][0] + bv, acc[i][1] + bv);
        float m1 = fmaxf(acc[i][2] + bv, acc[i][3] + bv);
        float o0 = fmaxf(m0, __shfl_xor(m0, 16, 64));
        float o1 = fmaxf(m1, __shfl_xor(m1, 16, 64));
        if (tx < 16) {
            int m = rp * 32 + tx * 2;
            float2 st2 = make_float2(o0, o1);
            *reinterpret_cast<float2*>(
                &outp[((long)(b * ICC + oc0 + ty * 8 + i)) * MM + m]) = st2;
        }
    }
}

// ---------------- s_p = w_p . pooled phi ----------------
__global__ void k_spdot(const float* __restrict__ phip,
                        const float* __restrict__ cp_w, float* __restrict__ sp) {
    int b = blockIdx.y;
    int m = blockIdx.x * 256 + threadIdx.x;
    float acc = 0.f;
    for (int c = 0; c < ICC; ++c)
        acc += cp_w[ICC + c] * phip[((long)(b * ICC + c)) * MM + m];
    sp[b * MM + m] = acc;
}

// ---------------- s_t[b,n] = weff . x[b,:,n] + bt ----------------
__global__ __launch_bounds__(256) void k_st(const float* __restrict__ x,
                                            const float* __restrict__ weff,
                                            float* __restrict__ st) {
    __shared__ float wl[256];
    int b = blockIdx.y, t = threadIdx.x;
    int n = blockIdx.x * 256 + t;
    wl[t] = weff[t];
    __syncthreads();
    float acc = 0.f;
    const float* xb = x + (long)b * CC * NN + n;
#pragma unroll 8
    for (int c = 0; c < CC; ++c) acc += wl[c] * xb[(long)c * NN];
    st[b * NN + n] = acc + weff[256];
}

// ---------------- fused P kernel -------------------------------------------
// P[b][o][n] = sum_m relu(st[n]+sp[m]) * gq[b][m][o],
// gq[b][m][o] = sum_c Ww[o][c] * gp[b][c][m]   (computed per m-tile in LDS)
// grid (32 n-tiles, 4 o-tiles, 8 b), block (32,8). P -> d_out.
__global__ __launch_bounds__(256) void k_pgemm2(
    const float* __restrict__ st, const float* __restrict__ sp,
    const float* __restrict__ gp, const float* __restrict__ Ww,
    float* __restrict__ P) {
    __shared__ float WwT[128][64];   // [c][o]  32 KB, staged once
    __shared__ float gpT[128][16];   // [c][mm]
    __shared__ float Fs[16][128];    // [mm][n]
    __shared__ float Gq[16][64];     // [mm][o]
    __shared__ float spL[1024];
    __shared__ float stL[128];
    const int tx = threadIdx.x, ty = threadIdx.y;
    const int tid = ty * 32 + tx;
    const int n0 = blockIdx.x * 128, o0 = blockIdx.y * 64, b = blockIdx.z;

#pragma unroll
    for (int r = 0; r < 32; ++r) {
        int flat = r * 256 + tid;          // 0..8191
        int o = flat >> 7, c = flat & 127;
        WwT[c][o] = Ww[(o0 + o) * ICC + c];
    }
#pragma unroll
    for (int r = 0; r < 4; ++r) spL[r * 256 + tid] = sp[b * MM + r * 256 + tid];
    if (tid < 128) stL[tid] = st[b * NN + n0 + tid];
    __syncthreads();

    float acc[8][4];
#pragma unroll
    for (int i = 0; i < 8; ++i)
#pragma unroll
        for (int j = 0; j < 4; ++j) acc[i][j] = 0.f;

    for (int k0 = 0; k0 < MM; k0 += 16) {
#pragma unroll
        for (int r = 0; r < 8; ++r) {
            int idx = r * 256 + tid;
            int c = idx >> 4, mm = idx & 15;
            gpT[c][mm] = gp[((long)(b * ICC + c)) * MM + k0 + mm];
        }
#pragma unroll
        for (int r = 0; r < 8; ++r) {
            int idx = r * 256 + tid;
            int kk = idx >> 7, px = idx & 127;
            Fs[kk][px] = fmaxf(stL[px] + spL[k0 + kk], 0.f);
        }
        __syncthreads();
        // Gq tile: 16m x 64o, each thread 4 entries, 128-deep dot
#pragma unroll
        for (int s = 0; s < 4; ++s) {
            int flat = s * 256 + tid;
            int mm = flat >> 6, o = flat & 63;
            float a = 0.f;
#pragma unroll 8
            for (int c = 0; c < 128; ++c) a += gpT[c][mm] * WwT[c][o];
            Gq[mm][o] = a;
        }
        __syncthreads();
#pragma unroll
        for (int kk = 0; kk < 16; ++kk) {
            float4 xv = *reinterpret_cast<const float4*>(&Fs[kk][tx * 4]);
            float4 w0 = *reinterpret_cast<const float4*>(&Gq[kk][ty * 8]);
            float4 w1 = *reinterpret_cast<const float4*>(&Gq[kk][ty * 8 + 4]);
            const float wv[8] = {w0.x, w0.y, w0.z, w0.w, w1.x, w1.y, w1.z, w1.w};
#pragma unroll
            for (int i = 0; i < 8; ++i) {
                acc[i][0] += wv[i] * xv.x;
                acc[i][1] += wv[i] * xv.y;
                acc[i][2] += wv[i] * xv.z;
                acc[i][3] += wv[i] * xv.w;
            }
        }
        __syncthreads();
    }
#pragma unroll
    for (int i = 0; i < 8; ++i) {
        float4 v = make_float4(acc[i][0], acc[i][1], acc[i][2], acc[i][3]);
        *reinterpret_cast<float4*>(
            &P[((long)(b * CC + o0 + ty * 8 + i)) * NN + n0 + tx * 4]) = v;
    }
}

// ---------------- per-channel sum / sumsq of P (double) ---------------------
__global__ __launch_bounds__(256) void k_bnstats(const float* __restrict__ P,
                                                 double* __restrict__ sacc,
                                                 double* __restrict__ sacc2) {
    int o = blockIdx.x, b = blockIdx.y, t = threadIdx.x;
    const float* p = P + ((long)(b * CC + o)) * NN;
    double s = 0.0, s2 = 0.0;
    for (int i = t; i < NN; i += 256) {
        double v = (double)p[i];
        s += v;
        s2 += v * v;
    }
#pragma unroll
    for (int off = 32; off > 0; off >>= 1) {
        s += __shfl_down(s, off, 64);
        s2 += __shfl_down(s2, off, 64);
    }
    __shared__ double rs[4], rs2[4];
    int lane = t & 63, w = t >> 6;
    if (lane == 0) { rs[w] = s; rs2[w] = s2; }
    __syncthreads();
    if (t == 0) {
        atomicAdd(&sacc[o], rs[0] + rs[1] + rs[2] + rs[3]);
        atomicAdd(&sacc2[o], rs2[0] + rs2[1] + rs2[2] + rs2[3]);
    }
}

// ---------------- BN scale/shift ----------------
__global__ void k_bnfin2(const double* __restrict__ sacc,
                         const double* __restrict__ sacc2,
                         const float* __restrict__ Wb,
                         const float* __restrict__ gamma,
                         const float* __restrict__ beta,
                         float* __restrict__ ab) {
    int o = threadIdx.x;
    double sp = sacc[o], sp2 = sacc2[o];
    double invBN = 1.0 / (double)(BB * NN);
    double mP = sp * invBN;                   // E[P]
    double varP = sp2 * invBN - mP * mP;      // Var(P)
    if (varP < 0.0) varP = 0.0;
    double wb = (double)Wb[o];
    double mean = mP / (double)MM + wb;       // E[w_y]
    double var = varP / ((double)MM * (double)MM);
    double A = (double)gamma[o] / sqrt(var + (double)BN_EPS);
    ab[o] = (float)(A / (double)MM);
    ab[256 + o] = (float)((wb - mean) * A + (double)beta[o]);
}

// ---------------- finalize in place: out = P*am + sh + x ----------------
__global__ __launch_bounds__(256) void k_final2(const float* __restrict__ x,
                                                const float* __restrict__ ab,
                                                float* __restrict__ out) {
    long i4 = (long)blockIdx.x * 256 + threadIdx.x;
    long idx = i4 * 4;
    int o = (int)((idx >> 12) & 255);  // (idx / 4096) % 256
    float am = ab[o], sh = ab[256 + o];
    float4 p = *reinterpret_cast<const float4*>(&out[idx]);
    float4 xv = *reinterpret_cast<const float4*>(&x[idx]);
    float4 r;
    r.x = fmaf(p.x, am, sh) + xv.x;
    r.y = fmaf(p.y, am, sh) + xv.y;
    r.z = fmaf(p.z, am, sh) + xv.z;
    r.w = fmaf(p.w, am, sh) + xv.w;
    *reinterpret_cast<float4*>(&out[idx]) = r;
}

extern "C" void kernel_launch(void* const* d_in, const int* in_sizes, int n_in,
                              void* d_out, int out_size, void* d_ws, size_t ws_size,
                              hipStream_t stream) {
    const float* x       = (const float*)d_in[0];
    const float* g_w     = (const float*)d_in[1];
    const float* g_b     = (const float*)d_in[2];
    const float* theta_w = (const float*)d_in[3];
    const float* theta_b = (const float*)d_in[4];
    const float* phi_w   = (const float*)d_in[5];
    const float* phi_b   = (const float*)d_in[6];
    const float* cp_w    = (const float*)d_in[7];
    const float* W_w     = (const float*)d_in[8];
    const float* W_b     = (const float*)d_in[9];
    const float* bn_g    = (const float*)d_in[10];
    const float* bn_b    = (const float*)d_in[11];
    float* out = (float*)d_out;
    float* ws = (float*)d_ws;

    float* weff   = ws + WS_WT;
    float* sps    = ws + WS_SPS;
    float* st     = ws + WS_ST;
    double* sacc  = (double*)(ws + WS_SACC);
    double* sacc2 = (double*)(ws + WS_SACC2);
    float* ab     = ws + WS_AB;
    float* gp     = ws + WS_GP;
    float* phid   = out;  // stage pooled phi in d_out (dead before P is written)

    hipMemsetAsync(sacc, 0, 2 * 256 * sizeof(double), stream);

    k_weff<<<1, 256, 0, stream>>>(cp_w, theta_w, theta_b, weff);
    k_convpool<<<dim3(32, 2, 8), dim3(32, 8), 0, stream>>>(x, g_w, g_b, gp);
    k_convpool<<<dim3(32, 2, 8), dim3(32, 8), 0, stream>>>(x, phi_w, phi_b, phid);
    k_spdot<<<dim3(4, 8), 256, 0, stream>>>(phid, cp_w, sps);
    k_st<<<dim3(16, 8), 256, 0, stream>>>(x, weff, st);
    k_pgemm2<<<dim3(32, 4, 8), dim3(32, 8), 0, stream>>>(st, sps, gp, W_w, out);
    k_bnstats<<<dim3(256, 8), 256, 0, stream>>>(out, sacc, sacc2);
    k_bnfin2<<<1, 256, 0, stream>>>(sacc, sacc2, W_b, bn_g, bn_b, ab);
    k_final2<<<8192, 256, 0, stream>>>(x, ab, out);
}

// Round 9
// 467.434 us; speedup vs baseline: 2.9707x; 2.9707x over previous
//
#include <hip/hip_runtime.h>
#include <hip/hip_bf16.h>

// Problem constants
#define BB 8
#define CC 256
#define ICC 128
#define HH 64
#define WW 64
#define NN 4096   // HH*WW
#define MM 1024   // pooled
#define BN_EPS 1e-5

// ---------------- workspace layout (float offsets) --------------------------
// Path B (always valid):   0 .. 1,114,112 floats  (4.25 MB)
// Path A (ws_size >= ~12.85MB): adds gq at 1,114,112 .. 3,211,264 floats
#define WS_WT    0L         // weff[256], bias at [256]
#define WS_SPS   1024L      // 8*1024 s_p
#define WS_ST    16384L     // 8*4096 s_t
#define WS_SACC  49152L     // double[256] sum(P)   (512 floats)
#define WS_SACC2 49664L     // double[256] sum(P^2) (512 floats)
#define WS_AB    50176L     // am[256], sh[256]
#define WS_GP    65536L     // 8*128*1024 pooled g  -> ends 1114112
#define WS_GQ    1114112L   // 8*1024*256 gq[b][m][o] -> ends 3211264
#define WS_A_END (3211264L * 4)   // bytes needed for Path A

// ---------------- collapsed theta weights -----------------------------------
__global__ void k_weff(const float* __restrict__ cp_w,
                       const float* __restrict__ theta_w,
                       const float* __restrict__ theta_b,
                       float* __restrict__ weff) {
    int ch = threadIdx.x;  // 0..255
    float acc = 0.f;
    for (int c = 0; c < ICC; ++c) acc += cp_w[c] * theta_w[c * CC + ch];
    weff[ch] = acc;
    if (ch == 0) {
        float bt = 0.f;
        for (int c = 0; c < ICC; ++c) bt += cp_w[c] * theta_b[c];
        weff[256] = bt;
    }
}

// ---------------- conv1x1 (128 out ch) + 2x2 maxpool, fp32 tiled ------------
__global__ __launch_bounds__(256) void k_convpool(
    const float* __restrict__ x, const float* __restrict__ w,
    const float* __restrict__ bias, float* __restrict__ outp) {
    __shared__ float Xs[16][128];   // tx*4 <= 124 < 128: tx-dim is the WIDE dim
    __shared__ float WsT[16][64];   // ty*8+7 <= 63: ty-dim is the 64 dim
    const int tx = threadIdx.x, ty = threadIdx.y;
    const int tid = ty * 32 + tx;
    const int rp = blockIdx.x;
    const int oc0 = blockIdx.y * 64;
    const int b = blockIdx.z;
    const long xbase = (long)b * CC * NN + rp * 128;

    float acc[8][4];
#pragma unroll
    for (int i = 0; i < 8; ++i)
#pragma unroll
        for (int j = 0; j < 4; ++j) acc[i][j] = 0.f;

    for (int k0 = 0; k0 < CC; k0 += 16) {
#pragma unroll
        for (int r = 0; r < 8; ++r) {
            int idx = r * 256 + tid;
            int kk = idx >> 7, px = idx & 127;
            Xs[kk][px] = x[xbase + (long)(k0 + kk) * NN + px];
        }
#pragma unroll
        for (int r = 0; r < 4; ++r) {
            int idx = r * 256 + tid;
            int kk = idx >> 6, oc = idx & 63;
            WsT[kk][oc] = w[(oc0 + oc) * CC + k0 + kk];
        }
        __syncthreads();
#pragma unroll
        for (int kk = 0; kk < 16; ++kk) {
            float4 xv = *reinterpret_cast<const float4*>(&Xs[kk][tx * 4]);
            float4 w0 = *reinterpret_cast<const float4*>(&WsT[kk][ty * 8]);
            float4 w1 = *reinterpret_cast<const float4*>(&WsT[kk][ty * 8 + 4]);
            const float wv[8] = {w0.x, w0.y, w0.z, w0.w, w1.x, w1.y, w1.z, w1.w};
#pragma unroll
            for (int i = 0; i < 8; ++i) {
                acc[i][0] += wv[i] * xv.x;
                acc[i][1] += wv[i] * xv.y;
                acc[i][2] += wv[i] * xv.z;
                acc[i][3] += wv[i] * xv.w;
            }
        }
        __syncthreads();
    }
#pragma unroll
    for (int i = 0; i < 8; ++i) {
        float bv = bias[oc0 + ty * 8 + i];
        float m0 = fmaxf(acc[i][0] + bv, acc[i][1] + bv);
        float m1 = fmaxf(acc[i][2] + bv, acc[i][3] + bv);
        float o0 = fmaxf(m0, __shfl_xor(m0, 16, 64));
        float o1 = fmaxf(m1, __shfl_xor(m1, 16, 64));
        if (tx < 16) {
            int m = rp * 32 + tx * 2;
            float2 st2 = make_float2(o0, o1);
            *reinterpret_cast<float2*>(
                &outp[((long)(b * ICC + oc0 + ty * 8 + i)) * MM + m]) = st2;
        }
    }
}

// ---------------- s_p = w_p . pooled phi ----------------
__global__ void k_spdot(const float* __restrict__ phip,
                        const float* __restrict__ cp_w, float* __restrict__ sp) {
    int b = blockIdx.y;
    int m = blockIdx.x * 256 + threadIdx.x;
    float acc = 0.f;
    for (int c = 0; c < ICC; ++c)
        acc += cp_w[ICC + c] * phip[((long)(b * ICC + c)) * MM + m];
    sp[b * MM + m] = acc;
}

// ---------------- s_t[b,n] = weff . x[b,:,n] + bt ----------------
__global__ __launch_bounds__(256) void k_st(const float* __restrict__ x,
                                            const float* __restrict__ weff,
                                            float* __restrict__ st) {
    __shared__ float wl[256];
    int b = blockIdx.y, t = threadIdx.x;
    int n = blockIdx.x * 256 + t;
    wl[t] = weff[t];
    __syncthreads();
    float acc = 0.f;
    const float* xb = x + (long)b * CC * NN + n;
#pragma unroll 8
    for (int c = 0; c < CC; ++c) acc += wl[c] * xb[(long)c * NN];
    st[b * NN + n] = acc + weff[256];
}

// ======================= PATH A: materialized gq =============================
// gq[b][m][o] = sum_c Ww[o][c] * gp[b][c][m]
// FIXED: consistent 64m x 128o tile. Old version read BsT[kk][tx*4] (tx*4<=127)
// from a 64-wide row (OOB LDS) and wrote o0+tx*4+j over a 64-wide o-tile
// (OOB global, cross-block race) -> the absmax~30-40 failures of R1/R4/R5/R8.
// grid (16 m-tiles, 2 o-tiles, 8 b), block (32,8): m = ty*8+i (64), o = tx*4+j (128)
__global__ __launch_bounds__(256) void k_gq(const float* __restrict__ gp,
                                            const float* __restrict__ Ww,
                                            float* __restrict__ gq) {
    __shared__ float As[16][64];    // [c][m]  (ty-dim, 64)
    __shared__ float BsT[16][128];  // [c][o]  (tx-dim, 128)
    const int tx = threadIdx.x, ty = threadIdx.y;
    const int tid = ty * 32 + tx;
    const int m0 = blockIdx.x * 64, o0 = blockIdx.y * 128, b = blockIdx.z;
    float acc[8][4];
#pragma unroll
    for (int i = 0; i < 8; ++i)
#pragma unroll
        for (int j = 0; j < 4; ++j) acc[i][j] = 0.f;

    for (int c0 = 0; c0 < ICC; c0 += 16) {
#pragma unroll
        for (int r = 0; r < 4; ++r) {
            int idx = r * 256 + tid;          // 0..1023 = 16c x 64m
            int kk = idx >> 6, mm = idx & 63;
            As[kk][mm] = gp[((long)(b * ICC + c0 + kk)) * MM + m0 + mm];
        }
#pragma unroll
        for (int r = 0; r < 8; ++r) {
            int idx = r * 256 + tid;          // 0..2047 = 16c x 128o
            int kk = idx >> 7, o = idx & 127;
            BsT[kk][o] = Ww[(o0 + o) * ICC + c0 + kk];
        }
        __syncthreads();
#pragma unroll
        for (int kk = 0; kk < 16; ++kk) {
            float4 bv = *reinterpret_cast<const float4*>(&BsT[kk][tx * 4]);     // o
            float4 a0 = *reinterpret_cast<const float4*>(&As[kk][ty * 8]);      // m
            float4 a1 = *reinterpret_cast<const float4*>(&As[kk][ty * 8 + 4]);
            const float av[8] = {a0.x, a0.y, a0.z, a0.w, a1.x, a1.y, a1.z, a1.w};
#pragma unroll
            for (int i = 0; i < 8; ++i) {
                acc[i][0] += av[i] * bv.x;
                acc[i][1] += av[i] * bv.y;
                acc[i][2] += av[i] * bv.z;
                acc[i][3] += av[i] * bv.w;
            }
        }
        __syncthreads();
    }
#pragma unroll
    for (int i = 0; i < 8; ++i) {
        float4 st4 = make_float4(acc[i][0], acc[i][1], acc[i][2], acc[i][3]);
        *reinterpret_cast<float4*>(
            &gq[((long)(b * MM + m0 + ty * 8 + i)) * CC + o0 + tx * 4]) = st4;
    }
}

// P[b][o][n] = sum_m relu(st[n]+sp[m]) * gq[b][m][o]; grid (32,4,8), block (32,8)
// tile 64o x 128n: o = ty*8+i (64-wide GqT), n = tx*4+j (128-wide Fs) — consistent
__global__ __launch_bounds__(256) void k_pgemm(
    const float* __restrict__ st, const float* __restrict__ sp,
    const float* __restrict__ gq, float* __restrict__ P) {
    __shared__ float Fs[16][128];   // [m][n]
    __shared__ float GqT[16][64];   // [m][o]
    __shared__ float spL[1024];
    __shared__ float stL[128];
    const int tx = threadIdx.x, ty = threadIdx.y;
    const int tid = ty * 32 + tx;
    const int n0 = blockIdx.x * 128, o0 = blockIdx.y * 64, b = blockIdx.z;

#pragma unroll
    for (int r = 0; r < 4; ++r) spL[r * 256 + tid] = sp[b * MM + r * 256 + tid];
    if (tid < 128) stL[tid] = st[b * NN + n0 + tid];
    __syncthreads();

    float acc[8][4];
#pragma unroll
    for (int i = 0; i < 8; ++i)
#pragma unroll
        for (int j = 0; j < 4; ++j) acc[i][j] = 0.f;

    for (int k0 = 0; k0 < MM; k0 += 16) {
#pragma unroll
        for (int r = 0; r < 8; ++r) {
            int idx = r * 256 + tid;
            int kk = idx >> 7, px = idx & 127;
            Fs[kk][px] = fmaxf(stL[px] + spL[k0 + kk], 0.f);
        }
#pragma unroll
        for (int r = 0; r < 4; ++r) {
            int idx = r * 256 + tid;
            int kk = idx >> 6, oc = idx & 63;
            GqT[kk][oc] = gq[((long)(b * MM + k0 + kk)) * CC + o0 + oc];
        }
        __syncthreads();
#pragma unroll
        for (int kk = 0; kk < 16; ++kk) {
            float4 xv = *reinterpret_cast<const float4*>(&Fs[kk][tx * 4]);
            float4 w0 = *reinterpret_cast<const float4*>(&GqT[kk][ty * 8]);
            float4 w1 = *reinterpret_cast<const float4*>(&GqT[kk][ty * 8 + 4]);
            const float wv[8] = {w0.x, w0.y, w0.z, w0.w, w1.x, w1.y, w1.z, w1.w};
#pragma unroll
            for (int i = 0; i < 8; ++i) {
                acc[i][0] += wv[i] * xv.x;
                acc[i][1] += wv[i] * xv.y;
                acc[i][2] += wv[i] * xv.z;
                acc[i][3] += wv[i] * xv.w;
            }
        }
        __syncthreads();
    }
#pragma unroll
    for (int i = 0; i < 8; ++i) {
        float4 v = make_float4(acc[i][0], acc[i][1], acc[i][2], acc[i][3]);
        *reinterpret_cast<float4*>(
            &P[((long)(b * CC + o0 + ty * 8 + i)) * NN + n0 + tx * 4]) = v;
    }
}

// ======================= PATH B: fused (R7's proven version) =================
__global__ __launch_bounds__(256) void k_pgemm2(
    const float* __restrict__ st, const float* __restrict__ sp,
    const float* __restrict__ gp, const float* __restrict__ Ww,
    float* __restrict__ P) {
    __shared__ float WwT[128][64];   // [c][o]
    __shared__ float gpT[128][16];   // [c][mm]
    __shared__ float Fs[16][128];    // [mm][n]
    __shared__ float Gq[16][64];     // [mm][o]
    __shared__ float spL[1024];
    __shared__ float stL[128];
    const int tx = threadIdx.x, ty = threadIdx.y;
    const int tid = ty * 32 + tx;
    const int n0 = blockIdx.x * 128, o0 = blockIdx.y * 64, b = blockIdx.z;

#pragma unroll
    for (int r = 0; r < 32; ++r) {
        int flat = r * 256 + tid;
        int o = flat >> 7, c = flat & 127;
        WwT[c][o] = Ww[(o0 + o) * ICC + c];
    }
#pragma unroll
    for (int r = 0; r < 4; ++r) spL[r * 256 + tid] = sp[b * MM + r * 256 + tid];
    if (tid < 128) stL[tid] = st[b * NN + n0 + tid];
    __syncthreads();

    float acc[8][4];
#pragma unroll
    for (int i = 0; i < 8; ++i)
#pragma unroll
        for (int j = 0; j < 4; ++j) acc[i][j] = 0.f;

    for (int k0 = 0; k0 < MM; k0 += 16) {
#pragma unroll
        for (int r = 0; r < 8; ++r) {
            int idx = r * 256 + tid;
            int c = idx >> 4, mm = idx & 15;
            gpT[c][mm] = gp[((long)(b * ICC + c)) * MM + k0 + mm];
        }
#pragma unroll
        for (int r = 0; r < 8; ++r) {
            int idx = r * 256 + tid;
            int kk = idx >> 7, px = idx & 127;
            Fs[kk][px] = fmaxf(stL[px] + spL[k0 + kk], 0.f);
        }
        __syncthreads();
#pragma unroll
        for (int s = 0; s < 4; ++s) {
            int flat = s * 256 + tid;
            int mm = flat >> 6, o = flat & 63;
            float a = 0.f;
#pragma unroll 8
            for (int c = 0; c < 128; ++c) a += gpT[c][mm] * WwT[c][o];
            Gq[mm][o] = a;
        }
        __syncthreads();
#pragma unroll
        for (int kk = 0; kk < 16; ++kk) {
            float4 xv = *reinterpret_cast<const float4*>(&Fs[kk][tx * 4]);
            float4 w0 = *reinterpret_cast<const float4*>(&Gq[kk][ty * 8]);
            float4 w1 = *reinterpret_cast<const float4*>(&Gq[kk][ty * 8 + 4]);
            const float wv[8] = {w0.x, w0.y, w0.z, w0.w, w1.x, w1.y, w1.z, w1.w};
#pragma unroll
            for (int i = 0; i < 8; ++i) {
                acc[i][0] += wv[i] * xv.x;
                acc[i][1] += wv[i] * xv.y;
                acc[i][2] += wv[i] * xv.z;
                acc[i][3] += wv[i] * xv.w;
            }
        }
        __syncthreads();
    }
#pragma unroll
    for (int i = 0; i < 8; ++i) {
        float4 v = make_float4(acc[i][0], acc[i][1], acc[i][2], acc[i][3]);
        *reinterpret_cast<float4*>(
            &P[((long)(b * CC + o0 + ty * 8 + i)) * NN + n0 + tx * 4]) = v;
    }
}

// ---------------- per-channel sum / sumsq of P (double) ---------------------
__global__ __launch_bounds__(256) void k_bnstats(const float* __restrict__ P,
                                                 double* __restrict__ sacc,
                                                 double* __restrict__ sacc2) {
    int o = blockIdx.x, b = blockIdx.y, t = threadIdx.x;
    const float* p = P + ((long)(b * CC + o)) * NN;
    double s = 0.0, s2 = 0.0;
    for (int i = t; i < NN; i += 256) {
        double v = (double)p[i];
        s += v;
        s2 += v * v;
    }
#pragma unroll
    for (int off = 32; off > 0; off >>= 1) {
        s += __shfl_down(s, off, 64);
        s2 += __shfl_down(s2, off, 64);
    }
    __shared__ double rs[4], rs2[4];
    int lane = t & 63, w = t >> 6;
    if (lane == 0) { rs[w] = s; rs2[w] = s2; }
    __syncthreads();
    if (t == 0) {
        atomicAdd(&sacc[o], rs[0] + rs[1] + rs[2] + rs[3]);
        atomicAdd(&sacc2[o], rs2[0] + rs2[1] + rs2[2] + rs2[3]);
    }
}

// ---------------- BN scale/shift ----------------
__global__ void k_bnfin2(const double* __restrict__ sacc,
                         const double* __restrict__ sacc2,
                         const float* __restrict__ Wb,
                         const float* __restrict__ gamma,
                         const float* __restrict__ beta,
                         float* __restrict__ ab) {
    int o = threadIdx.x;
    double sp = sacc[o], sp2 = sacc2[o];
    double invBN = 1.0 / (double)(BB * NN);
    double mP = sp * invBN;
    double varP = sp2 * invBN - mP * mP;
    if (varP < 0.0) varP = 0.0;
    double wb = (double)Wb[o];
    double mean = mP / (double)MM + wb;
    double var = varP / ((double)MM * (double)MM);
    double A = (double)gamma[o] / sqrt(var + (double)BN_EPS);
    ab[o] = (float)(A / (double)MM);
    ab[256 + o] = (float)((wb - mean) * A + (double)beta[o]);
}

// ---------------- finalize in place: out = P*am + sh + x ----------------
__global__ __launch_bounds__(256) void k_final2(const float* __restrict__ x,
                                                const float* __restrict__ ab,
                                                float* __restrict__ out) {
    long i4 = (long)blockIdx.x * 256 + threadIdx.x;
    long idx = i4 * 4;
    int o = (int)((idx >> 12) & 255);
    float am = ab[o], sh = ab[256 + o];
    float4 p = *reinterpret_cast<const float4*>(&out[idx]);
    float4 xv = *reinterpret_cast<const float4*>(&x[idx]);
    float4 r;
    r.x = fmaf(p.x, am, sh) + xv.x;
    r.y = fmaf(p.y, am, sh) + xv.y;
    r.z = fmaf(p.z, am, sh) + xv.z;
    r.w = fmaf(p.w, am, sh) + xv.w;
    *reinterpret_cast<float4*>(&out[idx]) = r;
}

extern "C" void kernel_launch(void* const* d_in, const int* in_sizes, int n_in,
                              void* d_out, int out_size, void* d_ws, size_t ws_size,
                              hipStream_t stream) {
    const float* x       = (const float*)d_in[0];
    const float* g_w     = (const float*)d_in[1];
    const float* g_b     = (const float*)d_in[2];
    const float* theta_w = (const float*)d_in[3];
    const float* theta_b = (const float*)d_in[4];
    const float* phi_w   = (const float*)d_in[5];
    const float* phi_b   = (const float*)d_in[6];
    const float* cp_w    = (const float*)d_in[7];
    const float* W_w     = (const float*)d_in[8];
    const float* W_b     = (const float*)d_in[9];
    const float* bn_g    = (const float*)d_in[10];
    const float* bn_b    = (const float*)d_in[11];
    float* out = (float*)d_out;
    float* ws = (float*)d_ws;

    float* weff   = ws + WS_WT;
    float* sps    = ws + WS_SPS;
    float* st     = ws + WS_ST;
    double* sacc  = (double*)(ws + WS_SACC);
    double* sacc2 = (double*)(ws + WS_SACC2);
    float* ab     = ws + WS_AB;
    float* gp     = ws + WS_GP;
    float* gq     = ws + WS_GQ;      // Path A only
    float* phid   = out;             // pooled phi staged in d_out (dead later)

    hipMemsetAsync(sacc, 0, 2 * 256 * sizeof(double), stream);

    k_weff<<<1, 256, 0, stream>>>(cp_w, theta_w, theta_b, weff);
    k_convpool<<<dim3(32, 2, 8), dim3(32, 8), 0, stream>>>(x, g_w, g_b, gp);
    k_convpool<<<dim3(32, 2, 8), dim3(32, 8), 0, stream>>>(x, phi_w, phi_b, phid);
    k_spdot<<<dim3(4, 8), 256, 0, stream>>>(phid, cp_w, sps);
    k_st<<<dim3(16, 8), 256, 0, stream>>>(x, weff, st);

    if (ws_size >= (size_t)WS_A_END) {
        // Path A: materialize gq once (fixed 64m x 128o tile)
        k_gq<<<dim3(16, 2, 8), dim3(32, 8), 0, stream>>>(gp, W_w, gq);
        k_pgemm<<<dim3(32, 4, 8), dim3(32, 8), 0, stream>>>(st, sps, gq, out);
    } else {
        // Path B: fused fallback — byte-identical to R7's passing kernel
        k_pgemm2<<<dim3(32, 4, 8), dim3(32, 8), 0, stream>>>(st, sps, gp, W_w, out);
    }

    k_bnstats<<<dim3(256, 8), 256, 0, stream>>>(out, sacc, sacc2);
    k_bnfin2<<<1, 256, 0, stream>>>(sacc, sacc2, W_b, bn_g, bn_b, ab);
    k_final2<<<8192, 256, 0, stream>>>(x, ab, out);
}

// Round 10
// 348.932 us; speedup vs baseline: 3.9795x; 1.3396x over previous
//
#include <hip/hip_runtime.h>
#include <hip/hip_bf16.h>

// Problem constants
#define BB 8
#define CC 256
#define ICC 128
#define NN 4096   // 64*64
#define MM 1024   // pooled
#define BN_EPS 1e-5

// ---------------- ws layout (float offsets; total 8.9 MB < proven 12.85 MB) -
#define WS_WT    0L         // weff[256], bias at [256]
#define WS_SPS   512L       // 8*1024 sorted s_p
#define WS_PERM  8704L      // 8*1024 int
#define WS_ST    16896L     // 8*4096 s_t
#define WS_KN    49664L     // 8*4096 int
#define WS_HIST  82432L     // 3*8*1025 = 24600 (reserve 24832)
#define WS_SACC  107264L    // double[256] (512 floats)
#define WS_SACC2 107776L    // double[256]
#define WS_AB    108288L    // am[256], sh[256]
#define WS_QWS   109056L    // float2[4*1025*256] = 2,099,200 floats -> 2,208,256
#define WS_TOT   2208256L   // float2[8*32*256] = 131,072 floats -> 2,339,328

// ---------------- out layout (floats; out = 8,388,608 floats) --------------
#define OUT_PHI  0L          // 1,048,576 pooled phi
#define OUT_GP   1048576L    // 1,048,576 pooled g
#define OUT_GQ   2097152L    // 2,097,152 gq[b][m][o] -> ends 4,194,304
#define OUT_QOUT 6289408L    // float2[4*1025*256] (batches 0..3) -> ends 8,388,608
#define QPB      262400L     // float2 per batch = 1025*256

// ---------------- collapsed theta weights -----------------------------------
__global__ void k_weff(const float* __restrict__ cp_w,
                       const float* __restrict__ theta_w,
                       const float* __restrict__ theta_b,
                       float* __restrict__ weff) {
    int ch = threadIdx.x;
    float acc = 0.f;
    for (int c = 0; c < ICC; ++c) acc += cp_w[c] * theta_w[c * CC + ch];
    weff[ch] = acc;
    if (ch == 0) {
        float bt = 0.f;
        for (int c = 0; c < ICC; ++c) bt += cp_w[c] * theta_b[c];
        weff[256] = bt;
    }
}

// ---------------- conv1x1 (128 oc) + 2x2 maxpool (proven) -------------------
__global__ __launch_bounds__(256) void k_convpool(
    const float* __restrict__ x, const float* __restrict__ w,
    const float* __restrict__ bias, float* __restrict__ outp) {
    __shared__ float Xs[16][128];
    __shared__ float WsT[16][64];
    const int tx = threadIdx.x, ty = threadIdx.y;
    const int tid = ty * 32 + tx;
    const int rp = blockIdx.x;
    const int oc0 = blockIdx.y * 64;
    const int b = blockIdx.z;
    const long xbase = (long)b * CC * NN + rp * 128;

    float acc[8][4];
#pragma unroll
    for (int i = 0; i < 8; ++i)
#pragma unroll
        for (int j = 0; j < 4; ++j) acc[i][j] = 0.f;

    for (int k0 = 0; k0 < CC; k0 += 16) {
#pragma unroll
        for (int r = 0; r < 8; ++r) {
            int idx = r * 256 + tid;
            int kk = idx >> 7, px = idx & 127;
            Xs[kk][px] = x[xbase + (long)(k0 + kk) * NN + px];
        }
#pragma unroll
        for (int r = 0; r < 4; ++r) {
            int idx = r * 256 + tid;
            int kk = idx >> 6, oc = idx & 63;
            WsT[kk][oc] = w[(oc0 + oc) * CC + k0 + kk];
        }
        __syncthreads();
#pragma unroll
        for (int kk = 0; kk < 16; ++kk) {
            float4 xv = *reinterpret_cast<const float4*>(&Xs[kk][tx * 4]);
            float4 w0 = *reinterpret_cast<const float4*>(&WsT[kk][ty * 8]);
            float4 w1 = *reinterpret_cast<const float4*>(&WsT[kk][ty * 8 + 4]);
            const float wv[8] = {w0.x, w0.y, w0.z, w0.w, w1.x, w1.y, w1.z, w1.w};
#pragma unroll
            for (int i = 0; i < 8; ++i) {
                acc[i][0] += wv[i] * xv.x;
                acc[i][1] += wv[i] * xv.y;
                acc[i][2] += wv[i] * xv.z;
                acc[i][3] += wv[i] * xv.w;
            }
        }
        __syncthreads();
    }
#pragma unroll
    for (int i = 0; i < 8; ++i) {
        float bv = bias[oc0 + ty * 8 + i];
        float m0 = fmaxf(acc[i][0] + bv, acc[i][1] + bv);
        float m1 = fmaxf(acc[i][2] + bv, acc[i][3] + bv);
        float o0 = fmaxf(m0, __shfl_xor(m0, 16, 64));
        float o1 = fmaxf(m1, __shfl_xor(m1, 16, 64));
        if (tx < 16) {
            int m = rp * 32 + tx * 2;
            float2 st2 = make_float2(o0, o1);
            *reinterpret_cast<float2*>(
                &outp[((long)(b * ICC + oc0 + ty * 8 + i)) * MM + m]) = st2;
        }
    }
}

// ---------------- s_p = w_p . pooled phi (proven) ---------------------------
__global__ void k_spdot(const float* __restrict__ phip,
                        const float* __restrict__ cp_w, float* __restrict__ sp) {
    int b = blockIdx.y;
    int m = blockIdx.x * 256 + threadIdx.x;
    float acc = 0.f;
    for (int c = 0; c < ICC; ++c)
        acc += cp_w[ICC + c] * phip[((long)(b * ICC + c)) * MM + m];
    sp[b * MM + m] = acc;
}

// ---------------- gq[b][m][o] = sum_c Ww[o][c]*gp[b][c][m] ------------------
// tile 32m x 128o, grid (32,2,8)=512 blocks (2/CU; old 64x128 grid was 1/CU).
// block (32,8): m = ty*4+i (<=31), o = tx*4+j (<=127). All bounds consistent.
__global__ __launch_bounds__(256) void k_gq2(const float* __restrict__ gp,
                                             const float* __restrict__ Ww,
                                             float* __restrict__ gq) {
    __shared__ float As[16][32];    // [c][m]
    __shared__ float BsT[16][128];  // [c][o]
    const int tx = threadIdx.x, ty = threadIdx.y;
    const int tid = ty * 32 + tx;
    const int m0 = blockIdx.x * 32, o0 = blockIdx.y * 128, b = blockIdx.z;
    float acc[4][4];
#pragma unroll
    for (int i = 0; i < 4; ++i)
#pragma unroll
        for (int j = 0; j < 4; ++j) acc[i][j] = 0.f;

    for (int c0 = 0; c0 < ICC; c0 += 16) {
#pragma unroll
        for (int r = 0; r < 2; ++r) {
            int idx = r * 256 + tid;          // 0..511 = 16c x 32m
            int kk = idx >> 5, mm = idx & 31;
            As[kk][mm] = gp[((long)(b * ICC + c0 + kk)) * MM + m0 + mm];
        }
#pragma unroll
        for (int r = 0; r < 8; ++r) {
            int idx = r * 256 + tid;          // 0..2047 = 16c x 128o
            int kk = idx >> 7, o = idx & 127;
            BsT[kk][o] = Ww[(o0 + o) * ICC + c0 + kk];
        }
        __syncthreads();
#pragma unroll
        for (int kk = 0; kk < 16; ++kk) {
            float4 bv = *reinterpret_cast<const float4*>(&BsT[kk][tx * 4]);
            float4 a  = *reinterpret_cast<const float4*>(&As[kk][ty * 4]);
            const float av[4] = {a.x, a.y, a.z, a.w};
#pragma unroll
            for (int i = 0; i < 4; ++i) {
                acc[i][0] += av[i] * bv.x;
                acc[i][1] += av[i] * bv.y;
                acc[i][2] += av[i] * bv.z;
                acc[i][3] += av[i] * bv.w;
            }
        }
        __syncthreads();
    }
#pragma unroll
    for (int i = 0; i < 4; ++i) {
        float4 v = make_float4(acc[i][0], acc[i][1], acc[i][2], acc[i][3]);
        *reinterpret_cast<float4*>(
            &gq[((long)(b * MM + m0 + ty * 4 + i)) * CC + o0 + tx * 4]) = v;
    }
}

// ---------------- bitonic sort s_p descending, keep perm --------------------
__global__ __launch_bounds__(1024) void k_sort(float* __restrict__ sps,
                                               int* __restrict__ perm) {
    __shared__ float v[1024];
    __shared__ int id[1024];
    int b = blockIdx.x, t = threadIdx.x;
    v[t] = sps[b * MM + t];
    id[t] = t;
    __syncthreads();
    for (int k = 2; k <= 1024; k <<= 1) {
        for (int j = k >> 1; j > 0; j >>= 1) {
            int ixj = t ^ j;
            if (ixj > t) {
                bool desc = ((t & k) == 0);
                float a = v[t], c = v[ixj];
                bool sw = desc ? (a < c) : (a > c);
                if (sw) {
                    v[t] = c; v[ixj] = a;
                    int tm = id[t]; id[t] = id[ixj]; id[ixj] = tm;
                }
            }
            __syncthreads();
        }
    }
    sps[b * MM + t] = v[t];
    perm[b * MM + t] = id[t];
}

// ---------------- prefix sums over sorted order -----------------------------
// Q[k][o] = {sum_{j<k} gq[perm_j][o], sum_{j<k} sp_j*gq[perm_j][o]}
__global__ void k_prefA(const float* __restrict__ gq, const int* __restrict__ perm,
                        const float* __restrict__ sps, float2* __restrict__ Qout,
                        float2* __restrict__ Qws, float2* __restrict__ tot) {
    int b = blockIdx.y, ch = blockIdx.x, o = threadIdx.x;
    float2* Q = (b < 4) ? (Qout + (long)b * QPB) : (Qws + (long)(b - 4) * QPB);
    if (ch == 0) Q[o] = make_float2(0.f, 0.f);
    float r1 = 0.f, r2 = 0.f;
    for (int j = ch * 32; j < ch * 32 + 32; ++j) {
        int mm = perm[b * MM + j];
        float vv = gq[((long)(b * MM + mm)) * CC + o];
        float s = sps[b * MM + j];
        r1 += vv;
        r2 += s * vv;
        Q[(long)(j + 1) * CC + o] = make_float2(r1, r2);
    }
    tot[(long)(b * 32 + ch) * CC + o] = make_float2(r1, r2);
}

__global__ void k_prefB(float2* __restrict__ tot) {
    int b = blockIdx.x, o = threadIdx.x;
    float o1 = 0.f, o2 = 0.f;
    for (int c = 0; c < 32; ++c) {
        long idx = (long)(b * 32 + c) * CC + o;
        float2 t = tot[idx];
        tot[idx] = make_float2(o1, o2);
        o1 += t.x;
        o2 += t.y;
    }
}

__global__ void k_prefC(float2* __restrict__ Qout, float2* __restrict__ Qws,
                        const float2* __restrict__ tot) {
    int b = blockIdx.y, ch = blockIdx.x, o = threadIdx.x;
    if (ch == 0) return;
    float2* Q = (b < 4) ? (Qout + (long)b * QPB) : (Qws + (long)(b - 4) * QPB);
    float2 off = tot[(long)(b * 32 + ch) * CC + o];
    for (int j = ch * 32; j < ch * 32 + 32; ++j) {
        long idx = (long)(j + 1) * CC + o;
        float2 q = Q[idx];
        q.x += off.x;
        q.y += off.y;
        Q[idx] = q;
    }
}

// ---------------- s_t, k_n = #{m: sp_sorted[m] > -s_t}, histogram -----------
__global__ __launch_bounds__(256) void k_stkn(
    const float* __restrict__ x, const float* __restrict__ weff,
    const float* __restrict__ sps, float* __restrict__ st, int* __restrict__ kn,
    float* __restrict__ hist) {
    __shared__ float spl[1024];
    __shared__ float wl[256];
    __shared__ float hc[1025], h1[1025], h2[1025];
    int b = blockIdx.y, t = threadIdx.x;
    int n = blockIdx.x * 256 + t;
    wl[t] = weff[t];
#pragma unroll
    for (int r = 0; r < 4; ++r) spl[r * 256 + t] = sps[b * MM + r * 256 + t];
    for (int i = t; i < 1025; i += 256) { hc[i] = 0.f; h1[i] = 0.f; h2[i] = 0.f; }
    __syncthreads();
    float acc = 0.f;
    const float* xb = x + (long)b * CC * NN + n;
#pragma unroll 8
    for (int c = 0; c < CC; ++c) acc += wl[c] * xb[(long)c * NN];
    acc += weff[256];
    float tval = -acc;
    int lo = 0, hi = 1024;
    while (lo < hi) {
        int mid = (lo + hi) >> 1;
        if (spl[mid] > tval) lo = mid + 1; else hi = mid;
    }
    st[b * NN + n] = acc;
    kn[b * NN + n] = lo;
    atomicAdd(&hc[lo], 1.0f);
    atomicAdd(&h1[lo], acc);
    atomicAdd(&h2[lo], acc * acc);
    __syncthreads();
    for (int i = t; i < 1025; i += 256) {
        if (hc[i] != 0.f) {
            atomicAdd(&hist[b * 1025 + i], hc[i]);
            atomicAdd(&hist[8 * 1025 + b * 1025 + i], h1[i]);
            atomicAdd(&hist[2 * 8 * 1025 + b * 1025 + i], h2[i]);
        }
    }
}

// ---------------- BN channel sums from histogram x Q tables (exact) ---------
__global__ void k_stats(const float2* __restrict__ Qout,
                        const float2* __restrict__ Qws,
                        const float* __restrict__ hist,
                        double* __restrict__ sacc, double* __restrict__ sacc2) {
    int b = blockIdx.y, kc = blockIdx.x, o = threadIdx.x;
    const float2* Q = (b < 4) ? (Qout + (long)b * QPB) : (Qws + (long)(b - 4) * QPB);
    double a1 = 0.0, a2 = 0.0;
    int k0 = kc * 129, k1 = k0 + 129;
    if (k1 > 1025) k1 = 1025;
    for (int k = k0; k < k1; ++k) {
        float ck = hist[b * 1025 + k];
        if (ck == 0.f) continue;
        float s1 = hist[8 * 1025 + b * 1025 + k];
        float s2 = hist[2 * 8 * 1025 + b * 1025 + k];
        float2 q = Q[(long)k * CC + o];
        a1 += (double)s1 * q.x + (double)ck * q.y;
        a2 += (double)s2 * q.x * q.x + 2.0 * (double)s1 * q.x * q.y +
              (double)ck * q.y * q.y;
    }
    atomicAdd(&sacc[o], a1);
    atomicAdd(&sacc2[o], a2);
}

// ---------------- BN scale/shift (proven) -----------------------------------
__global__ void k_bnfin2(const double* __restrict__ sacc,
                         const double* __restrict__ sacc2,
                         const float* __restrict__ Wb,
                         const float* __restrict__ gamma,
                         const float* __restrict__ beta,
                         float* __restrict__ ab) {
    int o = threadIdx.x;
    double sp = sacc[o], sp2 = sacc2[o];
    double invBN = 1.0 / (double)(BB * NN);
    double mP = sp * invBN;
    double varP = sp2 * invBN - mP * mP;
    if (varP < 0.0) varP = 0.0;
    double wb = (double)Wb[o];
    double mean = mP / (double)MM + wb;
    double var = varP / ((double)MM * (double)MM);
    double A = (double)gamma[o] / sqrt(var + (double)BN_EPS);
    ab[o] = (float)(A / (double)MM);
    ab[256 + o] = (float)((wb - mean) * A + (double)beta[o]);
}

// ---------------- final per batch: out = (st*Q1[kn]+Q2[kn])*am + sh + x -----
__global__ __launch_bounds__(256) void k_final3(
    const float* __restrict__ x, const float* __restrict__ st,
    const int* __restrict__ kn, const float2* __restrict__ Q,
    const float* __restrict__ ab, float* __restrict__ out, int b) {
    int i4 = blockIdx.x * 256 + threadIdx.x;   // 0..262143
    int idx = i4 * 4;                          // within-batch float index
    int o = idx >> 12;                         // 0..255
    int n = idx & 4095;
    float am = ab[o], sh = ab[256 + o];
    const int4 k4 = *reinterpret_cast<const int4*>(&kn[b * NN + n]);
    const float4 s4 = *reinterpret_cast<const float4*>(&st[b * NN + n]);
    float2 q0 = Q[(long)k4.x * CC + o];
    float2 q1 = Q[(long)k4.y * CC + o];
    float2 q2 = Q[(long)k4.z * CC + o];
    float2 q3 = Q[(long)k4.w * CC + o];
    long gidx = (long)b * CC * NN + idx;
    float4 xv = *reinterpret_cast<const float4*>(&x[gidx]);
    float4 r;
    r.x = fmaf(fmaf(s4.x, q0.x, q0.y), am, sh) + xv.x;
    r.y = fmaf(fmaf(s4.y, q1.x, q1.y), am, sh) + xv.y;
    r.z = fmaf(fmaf(s4.z, q2.x, q2.y), am, sh) + xv.z;
    r.w = fmaf(fmaf(s4.w, q3.x, q3.y), am, sh) + xv.w;
    *reinterpret_cast<float4*>(&out[gidx]) = r;
}

extern "C" void kernel_launch(void* const* d_in, const int* in_sizes, int n_in,
                              void* d_out, int out_size, void* d_ws, size_t ws_size,
                              hipStream_t stream) {
    const float* x       = (const float*)d_in[0];
    const float* g_w     = (const float*)d_in[1];
    const float* g_b     = (const float*)d_in[2];
    const float* theta_w = (const float*)d_in[3];
    const float* theta_b = (const float*)d_in[4];
    const float* phi_w   = (const float*)d_in[5];
    const float* phi_b   = (const float*)d_in[6];
    const float* cp_w    = (const float*)d_in[7];
    const float* W_w     = (const float*)d_in[8];
    const float* W_b     = (const float*)d_in[9];
    const float* bn_g    = (const float*)d_in[10];
    const float* bn_b    = (const float*)d_in[11];
    float* out = (float*)d_out;
    float* ws = (float*)d_ws;

    float* weff   = ws + WS_WT;
    float* sps    = ws + WS_SPS;
    int*   perm   = (int*)(ws + WS_PERM);
    float* st     = ws + WS_ST;
    int*   kn     = (int*)(ws + WS_KN);
    float* hist   = ws + WS_HIST;
    double* sacc  = (double*)(ws + WS_SACC);
    double* sacc2 = (double*)(ws + WS_SACC2);
    float* ab     = ws + WS_AB;
    float2* Qws   = (float2*)(ws + WS_QWS);
    float2* tot   = (float2*)(ws + WS_TOT);

    float* phid   = out + OUT_PHI;   // pooled phi (dead after spdot)
    float* gp     = out + OUT_GP;    // pooled g   (dead after gq2)
    float* gq     = out + OUT_GQ;    // gq         (dead after prefA)
    float2* Qout  = (float2*)(out + OUT_QOUT);  // Q batches 0..3

    hipMemsetAsync(hist, 0, 3 * 8 * 1025 * sizeof(float), stream);
    hipMemsetAsync(sacc, 0, 2 * 256 * sizeof(double), stream);

    k_weff<<<1, 256, 0, stream>>>(cp_w, theta_w, theta_b, weff);
    k_convpool<<<dim3(32, 2, 8), dim3(32, 8), 0, stream>>>(x, phi_w, phi_b, phid);
    k_spdot<<<dim3(4, 8), 256, 0, stream>>>(phid, cp_w, sps);
    k_convpool<<<dim3(32, 2, 8), dim3(32, 8), 0, stream>>>(x, g_w, g_b, gp);
    k_gq2<<<dim3(32, 2, 8), dim3(32, 8), 0, stream>>>(gp, W_w, gq);
    k_sort<<<8, 1024, 0, stream>>>(sps, perm);
    k_prefA<<<dim3(32, 8), 256, 0, stream>>>(gq, perm, sps, Qout, Qws, tot);
    k_prefB<<<8, 256, 0, stream>>>(tot);
    k_prefC<<<dim3(32, 8), 256, 0, stream>>>(Qout, Qws, tot);
    k_stkn<<<dim3(16, 8), 256, 0, stream>>>(x, weff, sps, st, kn, hist);
    k_stats<<<dim3(8, 8), 256, 0, stream>>>(Qout, Qws, hist, sacc, sacc2);
    k_bnfin2<<<1, 256, 0, stream>>>(sacc, sacc2, W_b, bn_g, bn_b, ab);

    // finals ascending b: each b's writes only clobber Q/gq/gp regions of
    // already-completed batches (verified offset arithmetic in journal).
    for (int b = 0; b < BB; ++b) {
        const float2* Qb = (b < 4) ? (Qout + (long)b * QPB) : (Qws + (long)(b - 4) * QPB);
        k_final3<<<1024, 256, 0, stream>>>(x, st, kn, Qb, ab, out, b);
    }
}